// Round 1
// baseline (3255.008 us; speedup 1.0000x reference)
//
#include <hip/hip_runtime.h>

#define N_NODES   100000
#define N_EDGES   1600000
#define D         64
#define NEG_SLOPE 0.2f

// ---- monotonic float<->uint encoding for atomicMax on float values ----
__device__ __forceinline__ unsigned enc_f(float x) {
    unsigned u = __float_as_uint(x);
    return (u & 0x80000000u) ? ~u : (u | 0x80000000u);
}
__device__ __forceinline__ float dec_f(unsigned k) {
    unsigned u = (k & 0x80000000u) ? (k & 0x7FFFFFFFu) : ~k;
    return __uint_as_float(u);
}
// encoded -inf: enc(0xFF800000) = ~0xFF800000 = 0x007FFFFF
#define ENC_NEG_INF 0x007FFFFFu

// ---- K0: init out=0, emax=-inf(enc), denom=0 (harness poisons ws/out to 0xAA) ----
__global__ void init_k(float* __restrict__ out, unsigned* __restrict__ emax,
                       float* __restrict__ denom) {
    int stride = gridDim.x * blockDim.x;
    for (int i = blockIdx.x * blockDim.x + threadIdx.x; i < N_NODES * D; i += stride)
        out[i] = 0.0f;
    for (int i = blockIdx.x * blockDim.x + threadIdx.x; i < N_NODES; i += stride) {
        emax[i]  = ENC_NEG_INF;
        denom[i] = 0.0f;
    }
}

// ---- K1: q = feat@Wq+bq ; k = feat@Wk+bk ; f = feat@Wf+bf ----
// 64 nodes per block; W matrices staged in LDS (48 KB). One wave = one node group.
#define NODES_PER_BLOCK 64
__global__ __launch_bounds__(256) void proj_k(
    const float* __restrict__ feat,
    const float* __restrict__ Wq, const float* __restrict__ bq,
    const float* __restrict__ Wk, const float* __restrict__ bk,
    const float* __restrict__ Wf, const float* __restrict__ bf,
    float* __restrict__ q, float* __restrict__ k, float* __restrict__ f) {

    __shared__ float Ws[3][D * D];
    __shared__ float bs[3][D];
    __shared__ float fs[4][D];

    for (int i = threadIdx.x; i < D * D; i += 256) {
        Ws[0][i] = Wq[i];
        Ws[1][i] = Wk[i];
        Ws[2][i] = Wf[i];
    }
    if (threadIdx.x < D) {
        bs[0][threadIdx.x] = bq[threadIdx.x];
        bs[1][threadIdx.x] = bk[threadIdx.x];
        bs[2][threadIdx.x] = bf[threadIdx.x];
    }

    const int d    = threadIdx.x & 63;
    const int sub  = threadIdx.x >> 6;   // 0..3 (one wave per sub)
    const int base = blockIdx.x * NODES_PER_BLOCK;

    for (int it = 0; it < NODES_PER_BLOCK; it += 4) {
        __syncthreads();
        int nload = base + it + sub;
        if (nload < N_NODES)
            fs[sub][d] = feat[(size_t)nload * D + d];
        __syncthreads();

        int n = base + it + sub;
        if (n < N_NODES) {
            float aq = bs[0][d], ak = bs[1][d], af = bs[2][d];
            #pragma unroll 16
            for (int i = 0; i < D; i++) {
                float x = fs[sub][i];
                aq += x * Ws[0][i * D + d];
                ak += x * Ws[1][i * D + d];
                af += x * Ws[2][i * D + d];
            }
            size_t o = (size_t)n * D + d;
            q[o] = aq; k[o] = ak; f[o] = af;
        }
    }
}

// ---- K2: per-edge logit e = leakyrelu(dot(k[src], q[dst])), atomicMax emax[dst] ----
// 8 lanes per edge, float4 loads, shfl reduction.
__global__ __launch_bounds__(256) void edge_logit_k(
    const int* __restrict__ src, const int* __restrict__ dst,
    const float* __restrict__ q, const float* __restrict__ k,
    float* __restrict__ e, unsigned* __restrict__ emax) {

    int t    = blockIdx.x * 256 + threadIdx.x;
    int eid  = t >> 3;
    int lane = t & 7;
    if (eid >= N_EDGES) return;

    int s  = src[eid];
    int dn = dst[eid];
    const float4* q4 = (const float4*)(q + (size_t)dn * D);
    const float4* k4 = (const float4*)(k + (size_t)s * D);
    float4 a0 = q4[lane * 2], a1 = q4[lane * 2 + 1];
    float4 b0 = k4[lane * 2], b1 = k4[lane * 2 + 1];
    float dot = a0.x * b0.x + a0.y * b0.y + a0.z * b0.z + a0.w * b0.w
              + a1.x * b1.x + a1.y * b1.y + a1.z * b1.z + a1.w * b1.w;
    dot += __shfl_xor(dot, 1);
    dot += __shfl_xor(dot, 2);
    dot += __shfl_xor(dot, 4);
    if (lane == 0) {
        float le = dot > 0.0f ? dot : NEG_SLOPE * dot;
        e[eid] = le;
        atomicMax(emax + dn, enc_f(le));
    }
}

// ---- K3: ez = exp(e - emax[dst]) in-place; denom[dst] += ez ----
__global__ __launch_bounds__(256) void edge_exp_k(
    const int* __restrict__ dst, float* __restrict__ e,
    const unsigned* __restrict__ emax, float* __restrict__ denom) {

    int eid = blockIdx.x * 256 + threadIdx.x;
    if (eid >= N_EDGES) return;
    int dn   = dst[eid];
    float m  = dec_f(emax[dn]);
    float ez = __expf(e[eid] - m);
    e[eid]   = ez;
    unsafeAtomicAdd(denom + dn, ez);
}

// ---- K4: out[dst] += (ez/denom[dst]) * f[src]  (8 lanes/edge, 8 atomics/lane) ----
__global__ __launch_bounds__(256) void aggregate_k(
    const int* __restrict__ src, const int* __restrict__ dst,
    const float* __restrict__ ez, const float* __restrict__ denom,
    const float* __restrict__ f, float* __restrict__ out) {

    int t    = blockIdx.x * 256 + threadIdx.x;
    int eid  = t >> 3;
    int lane = t & 7;
    if (eid >= N_EDGES) return;

    int s  = src[eid];
    int dn = dst[eid];
    float w = ez[eid] / denom[dn];
    const float4* f4 = (const float4*)(f + (size_t)s * D);
    float4 v0 = f4[lane * 2], v1 = f4[lane * 2 + 1];
    float* o = out + (size_t)dn * D + lane * 8;
    unsafeAtomicAdd(o + 0, w * v0.x);
    unsafeAtomicAdd(o + 1, w * v0.y);
    unsafeAtomicAdd(o + 2, w * v0.z);
    unsafeAtomicAdd(o + 3, w * v0.w);
    unsafeAtomicAdd(o + 4, w * v1.x);
    unsafeAtomicAdd(o + 5, w * v1.y);
    unsafeAtomicAdd(o + 6, w * v1.z);
    unsafeAtomicAdd(o + 7, w * v1.w);
}

extern "C" void kernel_launch(void* const* d_in, const int* in_sizes, int n_in,
                              void* d_out, int out_size, void* d_ws, size_t ws_size,
                              hipStream_t stream) {
    const float* feat = (const float*)d_in[0];
    const int*   src  = (const int*)d_in[1];
    const int*   dst  = (const int*)d_in[2];
    const float* Wq   = (const float*)d_in[3];
    const float* bq   = (const float*)d_in[4];
    const float* Wk   = (const float*)d_in[5];
    const float* bk   = (const float*)d_in[6];
    const float* Wf   = (const float*)d_in[7];
    const float* bf   = (const float*)d_in[8];
    float* out = (float*)d_out;

    // workspace layout (floats): q | k | f | e(=ez in-place) | emax(u32) | denom
    float*    q     = (float*)d_ws;
    float*    k     = q + (size_t)N_NODES * D;
    float*    f     = k + (size_t)N_NODES * D;
    float*    e     = f + (size_t)N_NODES * D;
    unsigned* emax  = (unsigned*)(e + N_EDGES);
    float*    denom = (float*)(emax + N_NODES);

    init_k<<<(N_NODES * D + 255) / 256, 256, 0, stream>>>(out, emax, denom);

    proj_k<<<(N_NODES + NODES_PER_BLOCK - 1) / NODES_PER_BLOCK, 256, 0, stream>>>(
        feat, Wq, bq, Wk, bk, Wf, bf, q, k, f);

    edge_logit_k<<<(N_EDGES * 8 + 255) / 256, 256, 0, stream>>>(src, dst, q, k, e, emax);

    edge_exp_k<<<(N_EDGES + 255) / 256, 256, 0, stream>>>(dst, e, emax, denom);

    aggregate_k<<<(N_EDGES * 8 + 255) / 256, 256, 0, stream>>>(src, dst, e, denom, f, out);
}

// Round 2
// 593.745 us; speedup vs baseline: 5.4822x; 5.4822x over previous
//
#include <hip/hip_runtime.h>
#include <math.h>

#define N_NODES   100000
#define N_EDGES   1600000
#define D         64
#define NEG_SLOPE 0.2f

// scan chunking: 256 threads x 4 elements = 1024 per block
#define SCAN_CHUNK 1024
#define NB_SCAN    ((N_NODES + SCAN_CHUNK - 1) / SCAN_CHUNK)   // 98

// ---- K0: zero counts + cursor (ws is poisoned to 0xAA before every call) ----
__global__ __launch_bounds__(256) void init_k(int* __restrict__ counts,
                                              int* __restrict__ cursor) {
    int i = blockIdx.x * 256 + threadIdx.x;
    if (i < N_NODES) { counts[i] = 0; cursor[i] = 0; }
}

// ---- K1: q = feat@Wq+bq ; k = feat@Wk+bk ; f = feat@Wf+bf ----
#define NODES_PER_BLOCK 64
__global__ __launch_bounds__(256) void proj_k(
    const float* __restrict__ feat,
    const float* __restrict__ Wq, const float* __restrict__ bq,
    const float* __restrict__ Wk, const float* __restrict__ bk,
    const float* __restrict__ Wf, const float* __restrict__ bf,
    float* __restrict__ q, float* __restrict__ k, float* __restrict__ f) {

    __shared__ float Ws[3][D * D];
    __shared__ float bs[3][D];
    __shared__ float fs[4][D];

    for (int i = threadIdx.x; i < D * D; i += 256) {
        Ws[0][i] = Wq[i];
        Ws[1][i] = Wk[i];
        Ws[2][i] = Wf[i];
    }
    if (threadIdx.x < D) {
        bs[0][threadIdx.x] = bq[threadIdx.x];
        bs[1][threadIdx.x] = bk[threadIdx.x];
        bs[2][threadIdx.x] = bf[threadIdx.x];
    }

    const int d    = threadIdx.x & 63;
    const int sub  = threadIdx.x >> 6;
    const int base = blockIdx.x * NODES_PER_BLOCK;

    for (int it = 0; it < NODES_PER_BLOCK; it += 4) {
        __syncthreads();
        int nload = base + it + sub;
        if (nload < N_NODES)
            fs[sub][d] = feat[(size_t)nload * D + d];
        __syncthreads();

        int n = base + it + sub;
        if (n < N_NODES) {
            float aq = bs[0][d], ak = bs[1][d], af = bs[2][d];
            #pragma unroll 16
            for (int i = 0; i < D; i++) {
                float x = fs[sub][i];
                aq += x * Ws[0][i * D + d];
                ak += x * Ws[1][i * D + d];
                af += x * Ws[2][i * D + d];
            }
            size_t o = (size_t)n * D + d;
            q[o] = aq; k[o] = ak; f[o] = af;
        }
    }
}

// ---- K2: histogram of dst ----
__global__ __launch_bounds__(256) void hist_k(const int* __restrict__ dst,
                                              int* __restrict__ counts) {
    int eid = blockIdx.x * 256 + threadIdx.x;
    if (eid < N_EDGES) atomicAdd(&counts[dst[eid]], 1);
}

// ---- K3a: per-block exclusive scan (1024 elems/block), blocksum out ----
__global__ __launch_bounds__(256) void scan1_k(const int* __restrict__ counts,
                                               int* __restrict__ rowstart,
                                               int* __restrict__ blocksum) {
    __shared__ int lds[256];
    int base = blockIdx.x * SCAN_CHUNK + threadIdx.x * 4;
    int c[4]; int s = 0;
    #pragma unroll
    for (int u = 0; u < 4; u++) {
        int idx = base + u;
        c[u] = (idx < N_NODES) ? counts[idx] : 0;
        s += c[u];
    }
    lds[threadIdx.x] = s;
    __syncthreads();
    for (int off = 1; off < 256; off <<= 1) {
        int v = (threadIdx.x >= off) ? lds[threadIdx.x - off] : 0;
        __syncthreads();
        lds[threadIdx.x] += v;
        __syncthreads();
    }
    int run = (threadIdx.x == 0) ? 0 : lds[threadIdx.x - 1];
    if (threadIdx.x == 255) blocksum[blockIdx.x] = lds[255];
    #pragma unroll
    for (int u = 0; u < 4; u++) {
        int idx = base + u;
        if (idx < N_NODES) rowstart[idx] = run;
        run += c[u];
    }
}

// ---- K3b: exclusive scan of the 98 block sums (single block) ----
__global__ __launch_bounds__(128) void scan2_k(int* __restrict__ blocksum) {
    __shared__ int lds[128];
    int t = threadIdx.x;
    lds[t] = (t < NB_SCAN) ? blocksum[t] : 0;
    __syncthreads();
    for (int off = 1; off < 128; off <<= 1) {
        int v = (t >= off) ? lds[t - off] : 0;
        __syncthreads();
        lds[t] += v;
        __syncthreads();
    }
    if (t < NB_SCAN) blocksum[t] = (t == 0) ? 0 : lds[t - 1];
}

// ---- K3c: add block offsets; close the CSR ----
__global__ __launch_bounds__(256) void scan3_k(int* __restrict__ rowstart,
                                               const int* __restrict__ blocksum) {
    int i = blockIdx.x * 256 + threadIdx.x;
    if (i < N_NODES) rowstart[i] += blocksum[i / SCAN_CHUNK];
    if (i == 0) rowstart[N_NODES] = N_EDGES;
}

// ---- K4: per-edge logit + scatter into CSR slot (8 lanes/edge) ----
__global__ __launch_bounds__(256) void scatter_logit_k(
    const int* __restrict__ src, const int* __restrict__ dst,
    const float* __restrict__ q, const float* __restrict__ k,
    const int* __restrict__ rowstart, int* __restrict__ cursor,
    float* __restrict__ eperm, int* __restrict__ srcperm) {

    int t    = blockIdx.x * 256 + threadIdx.x;
    int eid  = t >> 3;
    int lane = t & 7;
    if (eid >= N_EDGES) return;

    int s  = src[eid];
    int dn = dst[eid];
    const float4* q4 = (const float4*)(q + (size_t)dn * D);
    const float4* k4 = (const float4*)(k + (size_t)s * D);
    float4 a0 = q4[lane * 2], a1 = q4[lane * 2 + 1];
    float4 b0 = k4[lane * 2], b1 = k4[lane * 2 + 1];
    float dot = a0.x * b0.x + a0.y * b0.y + a0.z * b0.z + a0.w * b0.w
              + a1.x * b1.x + a1.y * b1.y + a1.z * b1.z + a1.w * b1.w;
    dot += __shfl_xor(dot, 1);
    dot += __shfl_xor(dot, 2);
    dot += __shfl_xor(dot, 4);
    if (lane == 0) {
        float le = dot > 0.0f ? dot : NEG_SLOPE * dot;
        int j = rowstart[dn] + atomicAdd(&cursor[dn], 1);
        eperm[j]   = le;
        srcperm[j] = s;
    }
}

// ---- K5: one wave per dst node: softmax over its edges + weighted f-sum ----
__global__ __launch_bounds__(256) void node_agg_k(
    const int* __restrict__ rowstart, const float* __restrict__ eperm,
    const int* __restrict__ srcperm, const float* __restrict__ f,
    float* __restrict__ out) {

    int wave = threadIdx.x >> 6;
    int lane = threadIdx.x & 63;
    int n    = blockIdx.x * 4 + wave;
    if (n >= N_NODES) return;

    int r0 = rowstart[n], r1 = rowstart[n + 1];
    float acc = 0.0f;

    if (r1 > r0) {
        // wave-wide max of logits
        float m = -INFINITY;
        for (int j = r0 + lane; j < r1; j += 64) m = fmaxf(m, eperm[j]);
        #pragma unroll
        for (int off = 32; off; off >>= 1) m = fmaxf(m, __shfl_xor(m, off));

        // wave-wide sum of exp
        float ssum = 0.0f;
        for (int j = r0 + lane; j < r1; j += 64) ssum += __expf(eperm[j] - m);
        #pragma unroll
        for (int off = 32; off; off >>= 1) ssum += __shfl_xor(ssum, off);
        float inv = 1.0f / ssum;

        // weighted accumulate: lane = feature dim, edges sequential
        for (int j = r0; j < r1; j++) {
            float w = __expf(eperm[j] - m) * inv;
            acc += w * f[(size_t)srcperm[j] * D + lane];
        }
    }
    out[(size_t)n * D + lane] = acc;
}

extern "C" void kernel_launch(void* const* d_in, const int* in_sizes, int n_in,
                              void* d_out, int out_size, void* d_ws, size_t ws_size,
                              hipStream_t stream) {
    const float* feat = (const float*)d_in[0];
    const int*   src  = (const int*)d_in[1];
    const int*   dst  = (const int*)d_in[2];
    const float* Wq   = (const float*)d_in[3];
    const float* bq   = (const float*)d_in[4];
    const float* Wk   = (const float*)d_in[5];
    const float* bk   = (const float*)d_in[6];
    const float* Wf   = (const float*)d_in[7];
    const float* bf   = (const float*)d_in[8];
    float* out = (float*)d_out;

    // workspace layout: q | k | f | eperm | srcperm | rowstart | counts | cursor | blocksum
    float* q        = (float*)d_ws;
    float* k        = q + (size_t)N_NODES * D;
    float* f        = k + (size_t)N_NODES * D;
    float* eperm    = f + (size_t)N_NODES * D;
    int*   srcperm  = (int*)(eperm + N_EDGES);
    int*   rowstart = srcperm + N_EDGES;              // N_NODES + 1
    int*   counts   = rowstart + N_NODES + 1;
    int*   cursor   = counts + N_NODES;
    int*   blocksum = cursor + N_NODES;               // NB_SCAN (<=128)

    init_k<<<(N_NODES + 255) / 256, 256, 0, stream>>>(counts, cursor);

    proj_k<<<(N_NODES + NODES_PER_BLOCK - 1) / NODES_PER_BLOCK, 256, 0, stream>>>(
        feat, Wq, bq, Wk, bk, Wf, bf, q, k, f);

    hist_k<<<(N_EDGES + 255) / 256, 256, 0, stream>>>(dst, counts);

    scan1_k<<<NB_SCAN, 256, 0, stream>>>(counts, rowstart, blocksum);
    scan2_k<<<1, 128, 0, stream>>>(blocksum);
    scan3_k<<<(N_NODES + 255) / 256, 256, 0, stream>>>(rowstart, blocksum);

    scatter_logit_k<<<(N_EDGES * 8 + 255) / 256, 256, 0, stream>>>(
        src, dst, q, k, rowstart, cursor, eperm, srcperm);

    node_agg_k<<<(N_NODES + 3) / 4, 256, 0, stream>>>(rowstart, eperm, srcperm, f, out);
}

// Round 3
// 409.693 us; speedup vs baseline: 7.9450x; 1.4492x over previous
//
#include <hip/hip_runtime.h>
#include <math.h>

#define N_NODES   100000
#define N_EDGES   1600000
#define D         64
#define NEG_SLOPE 0.2f

#define SCAN_CHUNK 1024
#define NB_SCAN    ((N_NODES + SCAN_CHUNK - 1) / SCAN_CHUNK)   // 98

#define AGG_CHUNK 128   // edges per online-softmax chunk (LDS buffered)

// ---- K0: zero counts (ws is poisoned to 0xAA before every call) ----
__global__ __launch_bounds__(256) void init_k(int* __restrict__ counts) {
    int i = blockIdx.x * 256 + threadIdx.x;
    if (i < N_NODES) counts[i] = 0;
}

// ---- K1: q = feat@Wq+bq ; k = feat@Wk+bk ; f = feat@Wf+bf ----
#define NODES_PER_BLOCK 64
__global__ __launch_bounds__(256) void proj_k(
    const float* __restrict__ feat,
    const float* __restrict__ Wq, const float* __restrict__ bq,
    const float* __restrict__ Wk, const float* __restrict__ bk,
    const float* __restrict__ Wf, const float* __restrict__ bf,
    float* __restrict__ q, float* __restrict__ k, float* __restrict__ f) {

    __shared__ float Ws[3][D * D];
    __shared__ float bs[3][D];
    __shared__ float fs[4][D];

    for (int i = threadIdx.x; i < D * D; i += 256) {
        Ws[0][i] = Wq[i];
        Ws[1][i] = Wk[i];
        Ws[2][i] = Wf[i];
    }
    if (threadIdx.x < D) {
        bs[0][threadIdx.x] = bq[threadIdx.x];
        bs[1][threadIdx.x] = bk[threadIdx.x];
        bs[2][threadIdx.x] = bf[threadIdx.x];
    }

    const int d    = threadIdx.x & 63;
    const int sub  = threadIdx.x >> 6;
    const int base = blockIdx.x * NODES_PER_BLOCK;

    for (int it = 0; it < NODES_PER_BLOCK; it += 4) {
        __syncthreads();
        int nload = base + it + sub;
        if (nload < N_NODES)
            fs[sub][d] = feat[(size_t)nload * D + d];
        __syncthreads();

        int n = base + it + sub;
        if (n < N_NODES) {
            float aq = bs[0][d], ak = bs[1][d], af = bs[2][d];
            #pragma unroll 16
            for (int i = 0; i < D; i++) {
                float x = fs[sub][i];
                aq += x * Ws[0][i * D + d];
                ak += x * Ws[1][i * D + d];
                af += x * Ws[2][i * D + d];
            }
            size_t o = (size_t)n * D + d;
            q[o] = aq; k[o] = ak; f[o] = af;
        }
    }
}

// ---- K2: histogram of dst; record each edge's intra-row slot ----
__global__ __launch_bounds__(256) void hist_k(const int* __restrict__ dst,
                                              int* __restrict__ counts,
                                              int* __restrict__ slot) {
    int eid = blockIdx.x * 256 + threadIdx.x;
    if (eid < N_EDGES) slot[eid] = atomicAdd(&counts[dst[eid]], 1);
}

// ---- K3a: per-block exclusive scan (1024 elems/block), blocksum out ----
__global__ __launch_bounds__(256) void scan1_k(const int* __restrict__ counts,
                                               int* __restrict__ rowstart,
                                               int* __restrict__ blocksum) {
    __shared__ int lds[256];
    int base = blockIdx.x * SCAN_CHUNK + threadIdx.x * 4;
    int c[4]; int s = 0;
    #pragma unroll
    for (int u = 0; u < 4; u++) {
        int idx = base + u;
        c[u] = (idx < N_NODES) ? counts[idx] : 0;
        s += c[u];
    }
    lds[threadIdx.x] = s;
    __syncthreads();
    for (int off = 1; off < 256; off <<= 1) {
        int v = (threadIdx.x >= off) ? lds[threadIdx.x - off] : 0;
        __syncthreads();
        lds[threadIdx.x] += v;
        __syncthreads();
    }
    int run = (threadIdx.x == 0) ? 0 : lds[threadIdx.x - 1];
    if (threadIdx.x == 255) blocksum[blockIdx.x] = lds[255];
    #pragma unroll
    for (int u = 0; u < 4; u++) {
        int idx = base + u;
        if (idx < N_NODES) rowstart[idx] = run;
        run += c[u];
    }
}

// ---- K3b: exclusive scan of the block sums (single block) ----
__global__ __launch_bounds__(128) void scan2_k(int* __restrict__ blocksum) {
    __shared__ int lds[128];
    int t = threadIdx.x;
    lds[t] = (t < NB_SCAN) ? blocksum[t] : 0;
    __syncthreads();
    for (int off = 1; off < 128; off <<= 1) {
        int v = (t >= off) ? lds[t - off] : 0;
        __syncthreads();
        lds[t] += v;
        __syncthreads();
    }
    if (t < NB_SCAN) blocksum[t] = (t == 0) ? 0 : lds[t - 1];
}

// ---- K3c: add block offsets; close the CSR ----
__global__ __launch_bounds__(256) void scan3_k(int* __restrict__ rowstart,
                                               const int* __restrict__ blocksum) {
    int i = blockIdx.x * 256 + threadIdx.x;
    if (i < N_NODES) rowstart[i] += blocksum[i / SCAN_CHUNK];
    if (i == 0) rowstart[N_NODES] = N_EDGES;
}

// ---- K4: scatter src into CSR slots (no atomics — slot precomputed) ----
__global__ __launch_bounds__(256) void scatter_k(
    const int* __restrict__ src, const int* __restrict__ dst,
    const int* __restrict__ slot, const int* __restrict__ rowstart,
    int* __restrict__ srcperm) {
    int eid = blockIdx.x * 256 + threadIdx.x;
    if (eid < N_EDGES)
        srcperm[rowstart[dst[eid]] + slot[eid]] = src[eid];
}

// ---- K5: fused per-node logits + online softmax + weighted f-aggregation ----
// One wave per dst node. Logit pass: 8 lanes/edge, float4 dot, shfl reduce.
// Softmax: flash-style online rescale over AGG_CHUNK-edge chunks (any degree).
// Accumulate: lane = feature dim, 4-way unrolled independent f-row gathers.
__global__ __launch_bounds__(256) void node_agg_k(
    const int* __restrict__ rowstart, const int* __restrict__ srcperm,
    const float* __restrict__ q, const float* __restrict__ k,
    const float* __restrict__ f, float* __restrict__ out) {

    __shared__ float lg[4][AGG_CHUNK];
    __shared__ int   si[4][AGG_CHUNK];

    int wave = threadIdx.x >> 6;
    int lane = threadIdx.x & 63;
    int n    = blockIdx.x * 4 + wave;
    if (n >= N_NODES) return;

    int r0 = rowstart[n], r1 = rowstart[n + 1];
    int len = r1 - r0;

    const int l8 = lane & 7;
    const float4* q4 = (const float4*)(q + (size_t)n * D);
    float4 qa = q4[l8 * 2], qb = q4[l8 * 2 + 1];

    float acc = 0.0f;
    float m = -INFINITY, l = 0.0f;

    for (int c0 = r0; c0 < r1; c0 += AGG_CHUNK) {
        int cnt = min(AGG_CHUNK, r1 - c0);

        // --- logit pass: 8 edges per wave-step ---
        for (int base = 0; base < cnt; base += 8) {
            int i = base + (lane >> 3);
            float dot = 0.0f;
            int sv = 0;
            if (i < cnt) {
                sv = srcperm[c0 + i];
                const float4* k4 = (const float4*)(k + (size_t)sv * D);
                float4 b0 = k4[l8 * 2], b1 = k4[l8 * 2 + 1];
                dot = qa.x * b0.x + qa.y * b0.y + qa.z * b0.z + qa.w * b0.w
                    + qb.x * b1.x + qb.y * b1.y + qb.z * b1.z + qb.w * b1.w;
            }
            dot += __shfl_xor(dot, 1);
            dot += __shfl_xor(dot, 2);
            dot += __shfl_xor(dot, 4);
            if (l8 == 0 && i < cnt) {
                lg[wave][i] = dot > 0.0f ? dot : NEG_SLOPE * dot;
                si[wave][i] = sv;
            }
        }
        __asm__ volatile("s_waitcnt lgkmcnt(0)" ::: "memory");

        // --- chunk max + online rescale ---
        float cm = -INFINITY;
        for (int i = lane; i < cnt; i += 64) cm = fmaxf(cm, lg[wave][i]);
        #pragma unroll
        for (int off = 32; off; off >>= 1) cm = fmaxf(cm, __shfl_xor(cm, off));
        float mnew  = fmaxf(m, cm);
        float scale = __expf(m - mnew);     // first chunk: exp(-inf)=0, harmless
        l   *= scale;
        acc *= scale;

        // --- exp + partial sum (exp stored back to LDS) ---
        float es = 0.0f;
        for (int i = lane; i < cnt; i += 64) {
            float ez = __expf(lg[wave][i] - mnew);
            lg[wave][i] = ez;
            es += ez;
        }
        #pragma unroll
        for (int off = 32; off; off >>= 1) es += __shfl_xor(es, off);
        l += es;
        m  = mnew;
        __asm__ volatile("s_waitcnt lgkmcnt(0)" ::: "memory");

        // --- weighted accumulate: lane = dim, 4-way unrolled ---
        int i = 0;
        for (; i + 4 <= cnt; i += 4) {
            float w0 = lg[wave][i],     w1 = lg[wave][i + 1];
            float w2 = lg[wave][i + 2], w3 = lg[wave][i + 3];
            int   s0 = si[wave][i],     s1 = si[wave][i + 1];
            int   s2 = si[wave][i + 2], s3 = si[wave][i + 3];
            float f0 = f[(size_t)s0 * D + lane];
            float f1 = f[(size_t)s1 * D + lane];
            float f2 = f[(size_t)s2 * D + lane];
            float f3 = f[(size_t)s3 * D + lane];
            acc += w0 * f0; acc += w1 * f1; acc += w2 * f2; acc += w3 * f3;
        }
        for (; i < cnt; i++)
            acc += lg[wave][i] * f[(size_t)si[wave][i] * D + lane];
    }

    float inv = (len > 0) ? 1.0f / l : 0.0f;
    out[(size_t)n * D + lane] = acc * inv;
}

extern "C" void kernel_launch(void* const* d_in, const int* in_sizes, int n_in,
                              void* d_out, int out_size, void* d_ws, size_t ws_size,
                              hipStream_t stream) {
    const float* feat = (const float*)d_in[0];
    const int*   src  = (const int*)d_in[1];
    const int*   dst  = (const int*)d_in[2];
    const float* Wq   = (const float*)d_in[3];
    const float* bq   = (const float*)d_in[4];
    const float* Wk   = (const float*)d_in[5];
    const float* bk   = (const float*)d_in[6];
    const float* Wf   = (const float*)d_in[7];
    const float* bf   = (const float*)d_in[8];
    float* out = (float*)d_out;

    // workspace layout: q | k | f | srcperm | slot | rowstart | counts | blocksum
    float* q        = (float*)d_ws;
    float* k        = q + (size_t)N_NODES * D;
    float* f        = k + (size_t)N_NODES * D;
    int*   srcperm  = (int*)(f + (size_t)N_NODES * D);
    int*   slot     = srcperm + N_EDGES;
    int*   rowstart = slot + N_EDGES;                 // N_NODES + 1
    int*   counts   = rowstart + N_NODES + 1;
    int*   blocksum = counts + N_NODES;               // NB_SCAN (<=128)

    init_k<<<(N_NODES + 255) / 256, 256, 0, stream>>>(counts);

    proj_k<<<(N_NODES + NODES_PER_BLOCK - 1) / NODES_PER_BLOCK, 256, 0, stream>>>(
        feat, Wq, bq, Wk, bk, Wf, bf, q, k, f);

    hist_k<<<(N_EDGES + 255) / 256, 256, 0, stream>>>(dst, counts, slot);

    scan1_k<<<NB_SCAN, 256, 0, stream>>>(counts, rowstart, blocksum);
    scan2_k<<<1, 128, 0, stream>>>(blocksum);
    scan3_k<<<(N_NODES + 255) / 256, 256, 0, stream>>>(rowstart, blocksum);

    scatter_k<<<(N_EDGES + 255) / 256, 256, 0, stream>>>(src, dst, slot, rowstart, srcperm);

    node_agg_k<<<(N_NODES + 3) / 4, 256, 0, stream>>>(rowstart, srcperm, q, k, f, out);
}

// Round 4
// 370.629 us; speedup vs baseline: 8.7824x; 1.1054x over previous
//
#include <hip/hip_runtime.h>
#include <math.h>

#define N_NODES   100000
#define N_EDGES   1600000
#define D         64
#define NEG_SLOPE 0.2f

#define SCAN_CHUNK 1024
#define NB_SCAN    ((N_NODES + SCAN_CHUNK - 1) / SCAN_CHUNK)   // 98

#define AGG_CHUNK 128   // edges per online-softmax chunk (LDS buffered)

// ---- K0: zero counts (ws is poisoned to 0xAA before every call) ----
__global__ __launch_bounds__(256) void init_k(int* __restrict__ counts) {
    int i = blockIdx.x * 256 + threadIdx.x;
    if (i < N_NODES) counts[i] = 0;
}

// ---- K1: q = feat@Wq+bq ; k = feat@Wk+bk ; f = feat@Wf+bf ----
// Register-resident W columns (192 VGPRs), feat broadcast via v_readlane.
// No LDS: inner loop is pure VALU (64 readlane + 192 fmac per node).
#define PROJ_CHUNK 32   // nodes per wave
__global__ __launch_bounds__(256, 2) void proj_k(
    const float* __restrict__ feat,
    const float* __restrict__ Wq, const float* __restrict__ bq,
    const float* __restrict__ Wk, const float* __restrict__ bk,
    const float* __restrict__ Wf, const float* __restrict__ bf,
    float* __restrict__ q, float* __restrict__ kk, float* __restrict__ f) {

    const int lane = threadIdx.x & 63;
    const int wave = threadIdx.x >> 6;

    // W columns for this lane's output dim, in registers
    float wq[D], wk[D], wf[D];
    #pragma unroll
    for (int i = 0; i < D; i++) {
        wq[i] = Wq[i * D + lane];
        wk[i] = Wk[i * D + lane];
        wf[i] = Wf[i * D + lane];
    }
    const float bqv = bq[lane], bkv = bk[lane], bfv = bf[lane];

    int n0 = (blockIdx.x * 4 + wave) * PROJ_CHUNK;
    int n1 = min(n0 + PROJ_CHUNK, N_NODES);

    for (int n = n0; n < n1; n += 2) {
        const bool two = (n + 1 < n1);
        float fv0 = feat[(size_t)n * D + lane];
        float fv1 = two ? feat[(size_t)(n + 1) * D + lane] : 0.0f;

        float aq0 = bqv, ak0 = bkv, af0 = bfv;
        float aq1 = bqv, ak1 = bkv, af1 = bfv;
        #pragma unroll
        for (int i = 0; i < D; i++) {
            float s0 = __int_as_float(__builtin_amdgcn_readlane(__float_as_int(fv0), i));
            float s1 = __int_as_float(__builtin_amdgcn_readlane(__float_as_int(fv1), i));
            aq0 = fmaf(s0, wq[i], aq0);
            ak0 = fmaf(s0, wk[i], ak0);
            af0 = fmaf(s0, wf[i], af0);
            aq1 = fmaf(s1, wq[i], aq1);
            ak1 = fmaf(s1, wk[i], ak1);
            af1 = fmaf(s1, wf[i], af1);
        }
        size_t o0 = (size_t)n * D + lane;
        q[o0] = aq0; kk[o0] = ak0; f[o0] = af0;
        if (two) {
            size_t o1 = (size_t)(n + 1) * D + lane;
            q[o1] = aq1; kk[o1] = ak1; f[o1] = af1;
        }
    }
}

// ---- K2: histogram of dst; record each edge's intra-row slot ----
__global__ __launch_bounds__(256) void hist_k(const int* __restrict__ dst,
                                              int* __restrict__ counts,
                                              int* __restrict__ slot) {
    int eid = blockIdx.x * 256 + threadIdx.x;
    if (eid < N_EDGES) slot[eid] = atomicAdd(&counts[dst[eid]], 1);
}

// ---- K3a: per-block exclusive scan (1024 elems/block), blocksum out ----
__global__ __launch_bounds__(256) void scan1_k(const int* __restrict__ counts,
                                               int* __restrict__ rowstart,
                                               int* __restrict__ blocksum) {
    __shared__ int lds[256];
    int base = blockIdx.x * SCAN_CHUNK + threadIdx.x * 4;
    int c[4]; int s = 0;
    #pragma unroll
    for (int u = 0; u < 4; u++) {
        int idx = base + u;
        c[u] = (idx < N_NODES) ? counts[idx] : 0;
        s += c[u];
    }
    lds[threadIdx.x] = s;
    __syncthreads();
    for (int off = 1; off < 256; off <<= 1) {
        int v = (threadIdx.x >= off) ? lds[threadIdx.x - off] : 0;
        __syncthreads();
        lds[threadIdx.x] += v;
        __syncthreads();
    }
    int run = (threadIdx.x == 0) ? 0 : lds[threadIdx.x - 1];
    if (threadIdx.x == 255) blocksum[blockIdx.x] = lds[255];
    #pragma unroll
    for (int u = 0; u < 4; u++) {
        int idx = base + u;
        if (idx < N_NODES) rowstart[idx] = run;
        run += c[u];
    }
}

// ---- K3b: exclusive scan of the block sums (single block) ----
__global__ __launch_bounds__(128) void scan2_k(int* __restrict__ blocksum) {
    __shared__ int lds[128];
    int t = threadIdx.x;
    lds[t] = (t < NB_SCAN) ? blocksum[t] : 0;
    __syncthreads();
    for (int off = 1; off < 128; off <<= 1) {
        int v = (t >= off) ? lds[t - off] : 0;
        __syncthreads();
        lds[t] += v;
        __syncthreads();
    }
    if (t < NB_SCAN) blocksum[t] = (t == 0) ? 0 : lds[t - 1];
}

// ---- K3c: add block offsets; close the CSR ----
__global__ __launch_bounds__(256) void scan3_k(int* __restrict__ rowstart,
                                               const int* __restrict__ blocksum) {
    int i = blockIdx.x * 256 + threadIdx.x;
    if (i < N_NODES) rowstart[i] += blocksum[i / SCAN_CHUNK];
    if (i == 0) rowstart[N_NODES] = N_EDGES;
}

// ---- K4: scatter src into CSR slots (no atomics — slot precomputed) ----
__global__ __launch_bounds__(256) void scatter_k(
    const int* __restrict__ src, const int* __restrict__ dst,
    const int* __restrict__ slot, const int* __restrict__ rowstart,
    int* __restrict__ srcperm) {
    int eid = blockIdx.x * 256 + threadIdx.x;
    if (eid < N_EDGES)
        srcperm[rowstart[dst[eid]] + slot[eid]] = src[eid];
}

// ---- K5: fused per-node logits + online softmax + weighted f-aggregation ----
__global__ __launch_bounds__(256) void node_agg_k(
    const int* __restrict__ rowstart, const int* __restrict__ srcperm,
    const float* __restrict__ q, const float* __restrict__ k,
    const float* __restrict__ f, float* __restrict__ out) {

    __shared__ float lg[4][AGG_CHUNK];
    __shared__ int   si[4][AGG_CHUNK];

    int wave = threadIdx.x >> 6;
    int lane = threadIdx.x & 63;
    int n    = blockIdx.x * 4 + wave;
    if (n >= N_NODES) return;

    int r0 = rowstart[n], r1 = rowstart[n + 1];
    int len = r1 - r0;

    const int l8 = lane & 7;
    const float4* q4 = (const float4*)(q + (size_t)n * D);
    float4 qa = q4[l8 * 2], qb = q4[l8 * 2 + 1];

    float acc = 0.0f;
    float m = -INFINITY, l = 0.0f;

    for (int c0 = r0; c0 < r1; c0 += AGG_CHUNK) {
        int cnt = min(AGG_CHUNK, r1 - c0);

        // --- logit pass: 8 edges per wave-step ---
        for (int base = 0; base < cnt; base += 8) {
            int i = base + (lane >> 3);
            float dot = 0.0f;
            int sv = 0;
            if (i < cnt) {
                sv = srcperm[c0 + i];
                const float4* k4 = (const float4*)(k + (size_t)sv * D);
                float4 b0 = k4[l8 * 2], b1 = k4[l8 * 2 + 1];
                dot = qa.x * b0.x + qa.y * b0.y + qa.z * b0.z + qa.w * b0.w
                    + qb.x * b1.x + qb.y * b1.y + qb.z * b1.z + qb.w * b1.w;
            }
            dot += __shfl_xor(dot, 1);
            dot += __shfl_xor(dot, 2);
            dot += __shfl_xor(dot, 4);
            if (l8 == 0 && i < cnt) {
                lg[wave][i] = dot > 0.0f ? dot : NEG_SLOPE * dot;
                si[wave][i] = sv;
            }
        }
        __asm__ volatile("s_waitcnt lgkmcnt(0)" ::: "memory");

        // --- chunk max + online rescale ---
        float cm = -INFINITY;
        for (int i = lane; i < cnt; i += 64) cm = fmaxf(cm, lg[wave][i]);
        #pragma unroll
        for (int off = 32; off; off >>= 1) cm = fmaxf(cm, __shfl_xor(cm, off));
        float mnew  = fmaxf(m, cm);
        float scale = __expf(m - mnew);
        l   *= scale;
        acc *= scale;

        // --- exp + partial sum (exp stored back to LDS) ---
        float es = 0.0f;
        for (int i = lane; i < cnt; i += 64) {
            float ez = __expf(lg[wave][i] - mnew);
            lg[wave][i] = ez;
            es += ez;
        }
        #pragma unroll
        for (int off = 32; off; off >>= 1) es += __shfl_xor(es, off);
        l += es;
        m  = mnew;
        __asm__ volatile("s_waitcnt lgkmcnt(0)" ::: "memory");

        // --- weighted accumulate: lane = dim, 4-way unrolled ---
        int i = 0;
        for (; i + 4 <= cnt; i += 4) {
            float w0 = lg[wave][i],     w1 = lg[wave][i + 1];
            float w2 = lg[wave][i + 2], w3 = lg[wave][i + 3];
            int   s0 = si[wave][i],     s1 = si[wave][i + 1];
            int   s2 = si[wave][i + 2], s3 = si[wave][i + 3];
            float f0 = f[(size_t)s0 * D + lane];
            float f1 = f[(size_t)s1 * D + lane];
            float f2 = f[(size_t)s2 * D + lane];
            float f3 = f[(size_t)s3 * D + lane];
            acc += w0 * f0; acc += w1 * f1; acc += w2 * f2; acc += w3 * f3;
        }
        for (; i < cnt; i++)
            acc += lg[wave][i] * f[(size_t)si[wave][i] * D + lane];
    }

    float inv = (len > 0) ? 1.0f / l : 0.0f;
    out[(size_t)n * D + lane] = acc * inv;
}

extern "C" void kernel_launch(void* const* d_in, const int* in_sizes, int n_in,
                              void* d_out, int out_size, void* d_ws, size_t ws_size,
                              hipStream_t stream) {
    const float* feat = (const float*)d_in[0];
    const int*   src  = (const int*)d_in[1];
    const int*   dst  = (const int*)d_in[2];
    const float* Wq   = (const float*)d_in[3];
    const float* bq   = (const float*)d_in[4];
    const float* Wk   = (const float*)d_in[5];
    const float* bk   = (const float*)d_in[6];
    const float* Wf   = (const float*)d_in[7];
    const float* bf   = (const float*)d_in[8];
    float* out = (float*)d_out;

    // workspace layout: q | k | f | srcperm | slot | rowstart | counts | blocksum
    float* q        = (float*)d_ws;
    float* k        = q + (size_t)N_NODES * D;
    float* f        = k + (size_t)N_NODES * D;
    int*   srcperm  = (int*)(f + (size_t)N_NODES * D);
    int*   slot     = srcperm + N_EDGES;
    int*   rowstart = slot + N_EDGES;                 // N_NODES + 1
    int*   counts   = rowstart + N_NODES + 1;
    int*   blocksum = counts + N_NODES;               // NB_SCAN (<=128)

    init_k<<<(N_NODES + 255) / 256, 256, 0, stream>>>(counts);

    proj_k<<<(N_NODES + 4 * PROJ_CHUNK - 1) / (4 * PROJ_CHUNK), 256, 0, stream>>>(
        feat, Wq, bq, Wk, bk, Wf, bf, q, k, f);

    hist_k<<<(N_EDGES + 255) / 256, 256, 0, stream>>>(dst, counts, slot);

    scan1_k<<<NB_SCAN, 256, 0, stream>>>(counts, rowstart, blocksum);
    scan2_k<<<1, 128, 0, stream>>>(blocksum);
    scan3_k<<<(N_NODES + 255) / 256, 256, 0, stream>>>(rowstart, blocksum);

    scatter_k<<<(N_EDGES + 255) / 256, 256, 0, stream>>>(src, dst, slot, rowstart, srcperm);

    node_agg_k<<<(N_NODES + 3) / 4, 256, 0, stream>>>(rowstart, srcperm, q, k, f, out);
}

// Round 6
// 295.389 us; speedup vs baseline: 11.0194x; 1.2547x over previous
//
#include <hip/hip_runtime.h>
#include <math.h>

#define N_NODES   100000
#define N_EDGES   1600000
#define D         64
#define NEG_SLOPE 0.2f

#define SCAN_CHUNK 1024
#define NB_SCAN    ((N_NODES + SCAN_CHUNK - 1) / SCAN_CHUNK)   // 98

#define AGG_CHUNK 128   // edges per online-softmax chunk (LDS buffered)

typedef __attribute__((ext_vector_type(8))) short short8;
typedef __attribute__((ext_vector_type(4))) float floatx4;
typedef _Float16 half2v __attribute__((ext_vector_type(2)));

// fp32 -> bf16 bits, round-to-nearest-even
__device__ __forceinline__ unsigned short bfbits(float x) {
    unsigned u = __float_as_uint(x);
    u += 0x7fffu + ((u >> 16) & 1u);
    return (unsigned short)(u >> 16);
}
__device__ __forceinline__ float bf2f(unsigned short b) {
    return __uint_as_float((unsigned)b << 16);
}
// fp32 -> fp16 bits
__device__ __forceinline__ unsigned short h16(float x) {
    _Float16 h = (_Float16)x;
    union { _Float16 h; unsigned short u; } c; c.h = h; return c.u;
}
// packed fp16 pair -> two fp32
__device__ __forceinline__ float2 hpair(unsigned v) {
    union { unsigned u; half2v h; } c; c.u = v;
    return make_float2((float)c.h[0], (float)c.h[1]);
}

// ---- K0: zero counts ----
__global__ __launch_bounds__(256) void init_k(int* __restrict__ counts) {
    int i = blockIdx.x * 256 + threadIdx.x;
    if (i < N_NODES) counts[i] = 0;
}

// ---- K1: MFMA projection ----
// q (fp32) and k (fp16) via SPLIT bf16 MFMA (hi/lo, 3 products/k-step -> fp32-quality);
// f (bf16) via plain bf16 MFMA (error-insensitive path: softmax weights sum to 1).
// Layouts (verified gfx950 16x16x32): A[m=lane&15][k=quad*8+j], B[n=lane&15][k=quad*8+j],
// D: col=lane&15, row=quad*4+reg.
#define WT_STRIDE 72            // bf16 elems; 144 B row stride
#define PROJ_BLOCKS 512
#define PROJ_WAVES  (PROJ_BLOCKS * 4)
// LDS slots: 0=Wq_hi 1=Wq_lo 2=Wk_hi 3=Wk_lo 4=Wf
__global__ __launch_bounds__(256, 1) void proj_k(
    const float* __restrict__ feat,
    const float* __restrict__ Wq, const float* __restrict__ bq,
    const float* __restrict__ Wk, const float* __restrict__ bk,
    const float* __restrict__ Wf, const float* __restrict__ bf,
    float* __restrict__ q, unsigned short* __restrict__ kh,
    unsigned short* __restrict__ fb) {

    __shared__ unsigned short wt[5 * 64 * WT_STRIDE];   // 46 KB

    const int tid  = threadIdx.x;
    const int lane = tid & 63;
    const int wave = tid >> 6;
    const int m    = lane & 15;
    const int quad = lane >> 4;

    // stage W^T hi/lo (Wq, Wk) and plain (Wf) into LDS as bf16
    for (int idx = tid; idx < 64 * 64; idx += 256) {
        int i = idx >> 6, d = idx & 63;                  // i = k-dim, d = out-dim
        int o = d * WT_STRIDE + i;
        float vq = Wq[idx];
        unsigned short qh = bfbits(vq);
        wt[0 * 64 * WT_STRIDE + o] = qh;
        wt[1 * 64 * WT_STRIDE + o] = bfbits(vq - bf2f(qh));
        float vk = Wk[idx];
        unsigned short khh = bfbits(vk);
        wt[2 * 64 * WT_STRIDE + o] = khh;
        wt[3 * 64 * WT_STRIDE + o] = bfbits(vk - bf2f(khh));
        wt[4 * 64 * WT_STRIDE + o] = bfbits(Wf[idx]);
    }
    __syncthreads();

    // register-resident B fragments + bias
    short8 Bf[5][4][2];
    float  bias[3][4];
    #pragma unroll
    for (int w = 0; w < 5; w++)
        #pragma unroll
        for (int nt = 0; nt < 4; nt++) {
            int n = nt * 16 + m;
            #pragma unroll
            for (int ks = 0; ks < 2; ks++)
                Bf[w][nt][ks] = *(const short8*)&wt[(w * 64 + n) * WT_STRIDE + ks * 32 + quad * 8];
        }
    #pragma unroll
    for (int nt = 0; nt < 4; nt++) {
        int n = nt * 16 + m;
        bias[0][nt] = bq[n]; bias[1][nt] = bk[n]; bias[2][nt] = bf[n];
    }

    const int NT  = (N_NODES + 15) / 16;   // 6250 (exact)
    const int wid = blockIdx.x * 4 + wave;

    for (int t = wid; t < NT; t += PROJ_WAVES) {
        int t0  = t * 16;
        int row = t0 + m; if (row > N_NODES - 1) row = N_NODES - 1;

        const floatx4* fr = (const floatx4*)(feat + (size_t)row * D + quad * 8);
        floatx4 x0 = fr[0], x1 = fr[1];    // k-dims quad*8..+7      (kstep 0)
        floatx4 x2 = fr[8], x3 = fr[9];    // k-dims 32+quad*8..+7   (kstep 1)

        short8 ah0, ah1, al0, al1;
        float xv[16] = {x0.x, x0.y, x0.z, x0.w, x1.x, x1.y, x1.z, x1.w,
                        x2.x, x2.y, x2.z, x2.w, x3.x, x3.y, x3.z, x3.w};
        #pragma unroll
        for (int j = 0; j < 8; j++) {
            unsigned short h0 = bfbits(xv[j]);
            ah0[j] = (short)h0;
            al0[j] = (short)bfbits(xv[j] - bf2f(h0));
            unsigned short h1 = bfbits(xv[8 + j]);
            ah1[j] = (short)h1;
            al1[j] = (short)bfbits(xv[8 + j] - bf2f(h1));
        }

        floatx4 accq[4], acck[4], accf[4];
        #pragma unroll
        for (int nt = 0; nt < 4; nt++) {
            floatx4 cq = {bias[0][nt], bias[0][nt], bias[0][nt], bias[0][nt]};
            cq = __builtin_amdgcn_mfma_f32_16x16x32_bf16(ah0, Bf[0][nt][0], cq, 0, 0, 0);
            cq = __builtin_amdgcn_mfma_f32_16x16x32_bf16(ah0, Bf[1][nt][0], cq, 0, 0, 0);
            cq = __builtin_amdgcn_mfma_f32_16x16x32_bf16(al0, Bf[0][nt][0], cq, 0, 0, 0);
            cq = __builtin_amdgcn_mfma_f32_16x16x32_bf16(ah1, Bf[0][nt][1], cq, 0, 0, 0);
            cq = __builtin_amdgcn_mfma_f32_16x16x32_bf16(ah1, Bf[1][nt][1], cq, 0, 0, 0);
            cq = __builtin_amdgcn_mfma_f32_16x16x32_bf16(al1, Bf[0][nt][1], cq, 0, 0, 0);
            accq[nt] = cq;

            floatx4 ck = {bias[1][nt], bias[1][nt], bias[1][nt], bias[1][nt]};
            ck = __builtin_amdgcn_mfma_f32_16x16x32_bf16(ah0, Bf[2][nt][0], ck, 0, 0, 0);
            ck = __builtin_amdgcn_mfma_f32_16x16x32_bf16(ah0, Bf[3][nt][0], ck, 0, 0, 0);
            ck = __builtin_amdgcn_mfma_f32_16x16x32_bf16(al0, Bf[2][nt][0], ck, 0, 0, 0);
            ck = __builtin_amdgcn_mfma_f32_16x16x32_bf16(ah1, Bf[2][nt][1], ck, 0, 0, 0);
            ck = __builtin_amdgcn_mfma_f32_16x16x32_bf16(ah1, Bf[3][nt][1], ck, 0, 0, 0);
            ck = __builtin_amdgcn_mfma_f32_16x16x32_bf16(al1, Bf[2][nt][1], ck, 0, 0, 0);
            acck[nt] = ck;

            floatx4 cf = {bias[2][nt], bias[2][nt], bias[2][nt], bias[2][nt]};
            cf = __builtin_amdgcn_mfma_f32_16x16x32_bf16(ah0, Bf[4][nt][0], cf, 0, 0, 0);
            cf = __builtin_amdgcn_mfma_f32_16x16x32_bf16(ah1, Bf[4][nt][1], cf, 0, 0, 0);
            accf[nt] = cf;
        }

        #pragma unroll
        for (int nt = 0; nt < 4; nt++) {
            int dim = nt * 16 + m;
            #pragma unroll
            for (int r = 0; r < 4; r++) {
                int node = t0 + quad * 4 + r;
                if (node < N_NODES) {
                    size_t o = (size_t)node * D + dim;
                    q[o]  = accq[nt][r];
                    kh[o] = h16(acck[nt][r]);
                    fb[o] = bfbits(accf[nt][r]);
                }
            }
        }
    }
}

// ---- K2: histogram of dst; record each edge's intra-row slot ----
__global__ __launch_bounds__(256) void hist_k(const int* __restrict__ dst,
                                              int* __restrict__ counts,
                                              int* __restrict__ slot) {
    int eid = blockIdx.x * 256 + threadIdx.x;
    if (eid < N_EDGES) slot[eid] = atomicAdd(&counts[dst[eid]], 1);
}

// ---- K3a: per-block exclusive scan (1024 elems/block), raw blocksum out ----
__global__ __launch_bounds__(256) void scan1_k(const int* __restrict__ counts,
                                               int* __restrict__ rowstart,
                                               int* __restrict__ blocksum) {
    __shared__ int lds[256];
    int base = blockIdx.x * SCAN_CHUNK + threadIdx.x * 4;
    int c[4]; int s = 0;
    #pragma unroll
    for (int u = 0; u < 4; u++) {
        int idx = base + u;
        c[u] = (idx < N_NODES) ? counts[idx] : 0;
        s += c[u];
    }
    lds[threadIdx.x] = s;
    __syncthreads();
    for (int off = 1; off < 256; off <<= 1) {
        int v = (threadIdx.x >= off) ? lds[threadIdx.x - off] : 0;
        __syncthreads();
        lds[threadIdx.x] += v;
        __syncthreads();
    }
    int run = (threadIdx.x == 0) ? 0 : lds[threadIdx.x - 1];
    if (threadIdx.x == 255) blocksum[blockIdx.x] = lds[255];
    #pragma unroll
    for (int u = 0; u < 4; u++) {
        int idx = base + u;
        if (idx < N_NODES) rowstart[idx] = run;
        run += c[u];
    }
}

// ---- K3b: add block offsets (each block scans the raw blocksums itself) ----
__global__ __launch_bounds__(256) void scan23_k(int* __restrict__ rowstart,
                                                const int* __restrict__ blocksum) {
    __shared__ int lds[128];
    int t = threadIdx.x;
    if (t < 128) lds[t] = (t < NB_SCAN) ? blocksum[t] : 0;
    __syncthreads();
    for (int off = 1; off < 128; off <<= 1) {
        int v = 0;
        if (t < 128 && t >= off) v = lds[t - off];
        __syncthreads();
        if (t < 128) lds[t] += v;
        __syncthreads();
    }
    int i = blockIdx.x * 256 + t;
    if (i < N_NODES) {
        int ci = i / SCAN_CHUNK;
        rowstart[i] += (ci ? lds[ci - 1] : 0);
    }
    if (i == 0) rowstart[N_NODES] = N_EDGES;
}

// ---- K4: scatter src into CSR slots (no atomics — slot precomputed) ----
__global__ __launch_bounds__(256) void scatter_k(
    const int* __restrict__ src, const int* __restrict__ dst,
    const int* __restrict__ slot, const int* __restrict__ rowstart,
    int* __restrict__ srcperm) {
    int eid = blockIdx.x * 256 + threadIdx.x;
    if (eid < N_EDGES)
        srcperm[rowstart[dst[eid]] + slot[eid]] = src[eid];
}

// ---- K5: fused per-node logits + online softmax + weighted f-aggregation ----
// k gathered as fp16 (precision-safe, half traffic); f as bf16; q fp32 sequential.
__global__ __launch_bounds__(256) void node_agg_k(
    const int* __restrict__ rowstart, const int* __restrict__ srcperm,
    const float* __restrict__ q, const unsigned short* __restrict__ kh,
    const unsigned short* __restrict__ fb, float* __restrict__ out) {

    __shared__ float lg[4][AGG_CHUNK];
    __shared__ int   si[4][AGG_CHUNK];

    int wave = threadIdx.x >> 6;
    int lane = threadIdx.x & 63;
    int n    = blockIdx.x * 4 + wave;
    if (n >= N_NODES) return;

    int r0 = rowstart[n], r1 = rowstart[n + 1];
    int len = r1 - r0;

    const int l8 = lane & 7;
    const float4* q4 = (const float4*)(q + (size_t)n * D + l8 * 8);
    float4 qa = q4[0], qb = q4[1];

    float acc = 0.0f;
    float m = -INFINITY, l = 0.0f;

    for (int c0 = r0; c0 < r1; c0 += AGG_CHUNK) {
        int cnt = min(AGG_CHUNK, r1 - c0);

        // --- logit pass: 8 edges per wave-step, fp16 k rows (16 B/lane) ---
        for (int base = 0; base < cnt; base += 8) {
            int i = base + (lane >> 3);
            float dot = 0.0f;
            int sv = 0;
            if (i < cnt) {
                sv = srcperm[c0 + i];
                uint4 u = *(const uint4*)(kh + (size_t)sv * D + l8 * 8);
                float2 p0 = hpair(u.x), p1 = hpair(u.y);
                float2 p2 = hpair(u.z), p3 = hpair(u.w);
                dot = qa.x * p0.x + qa.y * p0.y + qa.z * p1.x + qa.w * p1.y
                    + qb.x * p2.x + qb.y * p2.y + qb.z * p3.x + qb.w * p3.y;
            }
            dot += __shfl_xor(dot, 1);
            dot += __shfl_xor(dot, 2);
            dot += __shfl_xor(dot, 4);
            if (l8 == 0 && i < cnt) {
                lg[wave][i] = dot > 0.0f ? dot : NEG_SLOPE * dot;
                si[wave][i] = sv;
            }
        }
        __asm__ volatile("s_waitcnt lgkmcnt(0)" ::: "memory");

        // --- chunk max + online rescale ---
        float cm = -INFINITY;
        for (int i = lane; i < cnt; i += 64) cm = fmaxf(cm, lg[wave][i]);
        #pragma unroll
        for (int off = 32; off; off >>= 1) cm = fmaxf(cm, __shfl_xor(cm, off));
        float mnew  = fmaxf(m, cm);
        float scale = __expf(m - mnew);
        l   *= scale;
        acc *= scale;

        // --- exp + partial sum (exp stored back to LDS) ---
        float es = 0.0f;
        for (int i = lane; i < cnt; i += 64) {
            float ez = __expf(lg[wave][i] - mnew);
            lg[wave][i] = ez;
            es += ez;
        }
        #pragma unroll
        for (int off = 32; off; off >>= 1) es += __shfl_xor(es, off);
        l += es;
        m  = mnew;
        __asm__ volatile("s_waitcnt lgkmcnt(0)" ::: "memory");

        // --- weighted accumulate: lane = dim, bf16 f rows, 4-way unrolled ---
        int i = 0;
        for (; i + 4 <= cnt; i += 4) {
            float w0 = lg[wave][i],     w1 = lg[wave][i + 1];
            float w2 = lg[wave][i + 2], w3 = lg[wave][i + 3];
            int   s0 = si[wave][i],     s1 = si[wave][i + 1];
            int   s2 = si[wave][i + 2], s3 = si[wave][i + 3];
            float f0 = bf2f(fb[(size_t)s0 * D + lane]);
            float f1 = bf2f(fb[(size_t)s1 * D + lane]);
            float f2 = bf2f(fb[(size_t)s2 * D + lane]);
            float f3 = bf2f(fb[(size_t)s3 * D + lane]);
            acc += w0 * f0; acc += w1 * f1; acc += w2 * f2; acc += w3 * f3;
        }
        for (; i < cnt; i++)
            acc += lg[wave][i] * bf2f(fb[(size_t)si[wave][i] * D + lane]);
    }

    float inv = (len > 0) ? 1.0f / l : 0.0f;
    out[(size_t)n * D + lane] = acc * inv;
}

extern "C" void kernel_launch(void* const* d_in, const int* in_sizes, int n_in,
                              void* d_out, int out_size, void* d_ws, size_t ws_size,
                              hipStream_t stream) {
    const float* feat = (const float*)d_in[0];
    const int*   src  = (const int*)d_in[1];
    const int*   dst  = (const int*)d_in[2];
    const float* Wq   = (const float*)d_in[3];
    const float* bq   = (const float*)d_in[4];
    const float* Wk   = (const float*)d_in[5];
    const float* bk   = (const float*)d_in[6];
    const float* Wf   = (const float*)d_in[7];
    const float* bf   = (const float*)d_in[8];
    float* out = (float*)d_out;

    // workspace: q(f32) | kh(fp16) | fb(bf16) | srcperm | slot | rowstart | counts | blocksum
    float*          q        = (float*)d_ws;
    unsigned short* kh       = (unsigned short*)(q + (size_t)N_NODES * D);
    unsigned short* fb       = kh + (size_t)N_NODES * D;
    int*            srcperm  = (int*)(fb + (size_t)N_NODES * D);
    int*            slot     = srcperm + N_EDGES;
    int*            rowstart = slot + N_EDGES;            // N_NODES + 1
    int*            counts   = rowstart + N_NODES + 1;
    int*            blocksum = counts + N_NODES;          // NB_SCAN (<=128)

    init_k<<<(N_NODES + 255) / 256, 256, 0, stream>>>(counts);

    proj_k<<<PROJ_BLOCKS, 256, 0, stream>>>(
        feat, Wq, bq, Wk, bk, Wf, bf, q, kh, fb);

    hist_k<<<(N_EDGES + 255) / 256, 256, 0, stream>>>(dst, counts, slot);

    scan1_k<<<NB_SCAN, 256, 0, stream>>>(counts, rowstart, blocksum);
    scan23_k<<<(N_NODES + 255) / 256, 256, 0, stream>>>(rowstart, blocksum);

    scatter_k<<<(N_EDGES + 255) / 256, 256, 0, stream>>>(src, dst, slot, rowstart, srcperm);

    node_agg_k<<<(N_NODES + 3) / 4, 256, 0, stream>>>(rowstart, srcperm, q, kh, fb, out);
}